// Round 1
// baseline (55.433 us; speedup 1.0000x reference)
//
#include <hip/hip_runtime.h>
#include <math.h>

// MultiBiasEncoder: out[b,t,c] = sum_l loc_w[l] * ( sum_s scale_w[l,s] * LN_c(d_l*ws[s,:]+bs[s,:]*scales[s]) + loc_emb[l,c] )
// Closed-form LayerNorm stats: enc = d*w + k  =>  mean = d*mw + mk,
// var = d^2*Var(w) + 2d*Cov(w,k) + Var(k).  Fully elementwise per (pos, channel).

#define EPS_W 1e-6f
#define LN_EPS 1e-5f

constexpr int L = 5;
constexpr int S = 9;
constexpr int C = 64;

__device__ __forceinline__ float fastrcp(float v) { return __builtin_amdgcn_rcpf(v); }

__global__ __launch_bounds__(256) void mbe_kernel(
    const float* __restrict__ x,
    const float* __restrict__ ws,
    const float* __restrict__ bs,
    const float* __restrict__ loc_emb,
    const float* __restrict__ scales,
    const float* __restrict__ locs,
    float* __restrict__ out,
    int npos, int pos_per_wave)
{
    const int lane = threadIdx.x & 63;
    const int wave = blockIdx.x * (blockDim.x >> 6) + (threadIdx.x >> 6);
    const int c = lane;  // lane == channel

    // ---- per-lane table loads (all tables are tiny, L2/L3 resident) ----
    float w[S], k[S], rsc[S];
    float mw[S], mk[S], vw[S], cwk2[S], vk[S];
    float le[L], lc[L];
#pragma unroll
    for (int s = 0; s < S; ++s) {
        float sc = scales[s];
        rsc[s] = fastrcp(sc);
        w[s] = ws[s * C + c];
        k[s] = bs[s * C + c] * sc;
    }
#pragma unroll
    for (int l = 0; l < L; ++l) {
        le[l] = loc_emb[l * C + c];
        lc[l] = locs[l];
    }

    // ---- wave-wide LN stats per s (closed-form coefficients) ----
#pragma unroll
    for (int s = 0; s < S; ++s) {
        float sw_ = w[s], sk_ = k[s];
#pragma unroll
        for (int off = 32; off; off >>= 1) {
            sw_ += __shfl_xor(sw_, off);
            sk_ += __shfl_xor(sk_, off);
        }
        float mww = sw_ * (1.0f / 64.0f);
        float mkk = sk_ * (1.0f / 64.0f);
        float dw = w[s] - mww, dk = k[s] - mkk;
        float a = dw * dw, b = dw * dk, d2 = dk * dk;
#pragma unroll
        for (int off = 32; off; off >>= 1) {
            a += __shfl_xor(a, off);
            b += __shfl_xor(b, off);
            d2 += __shfl_xor(d2, off);
        }
        mw[s] = mww;
        mk[s] = mkk;
        vw[s] = a * (1.0f / 64.0f);
        cwk2[s] = b * (2.0f / 64.0f);
        vk[s] = d2 * (1.0f / 64.0f);
    }

    // ---- positions: each wave handles pos_per_wave contiguous positions ----
    for (int i = 0; i < pos_per_wave; ++i) {
        int p = wave * pos_per_wave + i;
        if (p >= npos) break;
        float xv = x[p];  // wave-uniform broadcast

        // location weights
        float d[L], lw[L];
        float lwsum = 0.0f;
#pragma unroll
        for (int l = 0; l < L; ++l) {
            d[l] = xv - lc[l];
            float ad = fabsf(d[l]);
            lw[l] = fastrcp(__logf(ad + 1.0f) + EPS_W);
            lwsum += lw[l];
        }
        float rlw = fastrcp(lwsum);

        float acc = 0.0f;
#pragma unroll
        for (int l = 0; l < L; ++l) {
            float dd = d[l];
            float ad = fabsf(dd);

            // scale weights
            float sw[S];
            float ssum = 0.0f;
#pragma unroll
            for (int s = 0; s < S; ++s) {
                float t = fabsf(__logf(fmaf(ad, rsc[s], EPS_W))) + EPS_W;
                sw[s] = fastrcp(t);
                ssum += sw[s];
            }
            float rss = fastrcp(ssum);

            // weighted sum over s of LayerNormed enc
            float inner = 0.0f;
#pragma unroll
            for (int s = 0; s < S; ++s) {
                float mean = fmaf(dd, mw[s], mk[s]);
                float var = fmaf(dd, fmaf(dd, vw[s], cwk2[s]), vk[s]);
                float rstd = rsqrtf(var + LN_EPS);
                float val = (fmaf(dd, w[s], k[s]) - mean) * rstd;
                inner = fmaf(val, sw[s] * rss, inner);
            }
            inner += le[l];
            acc = fmaf(inner, lw[l] * rlw, acc);
        }
        out[p * C + c] = acc;  // coalesced: lane c -> consecutive floats
    }
}

extern "C" void kernel_launch(void* const* d_in, const int* in_sizes, int n_in,
                              void* d_out, int out_size, void* d_ws, size_t ws_size,
                              hipStream_t stream) {
    const float* x = (const float*)d_in[0];
    const float* ws = (const float*)d_in[1];
    const float* bs = (const float*)d_in[2];
    const float* loc_emb = (const float*)d_in[3];
    const float* scales = (const float*)d_in[4];
    const float* locs = (const float*)d_in[5];
    float* out = (float*)d_out;

    int npos = in_sizes[0];  // B*T
    const int blocks = 1024;           // 256 thr = 4 waves each -> 4096 waves
    const int waves = blocks * 4;
    int ppw = (npos + waves - 1) / waves;
    mbe_kernel<<<blocks, 256, 0, stream>>>(x, ws, bs, loc_emb, scales, locs, out, npos, ppw);
}

// Round 2
// 14.445 us; speedup vs baseline: 3.8374x; 3.8374x over previous
//
#include <hip/hip_runtime.h>
#include <math.h>

// MultiBiasEncoder, coefficient-factored form.
// enc_{l,s,c} = d_l*w[s,c] + k[s,c],  k = bs*scales
// LN stats closed-form:  mean = d*mw + mk ;  var = d^2*vw + d*cwk2 + vk
// out[p,c] = sum_s A_s*w[s,c] + sum_s B_s*k[s,c] + sum_l lwn_l*le[l,c] + const_p
//   alpha_{l,s} = lwn_l * swn_{l,s} * rstd_{l,s}
//   A_s = sum_l alpha*d_l ; B_s = sum_l alpha ; const = -sum alpha*mean
// Phase A: 1 thread per position computes the 24 coefficients (all transcendentals once).
// Phase B: wave applies 24 FMAs per channel, coalesced store.

#define EPS_W 1e-6f
#define LN_EPS 1e-5f

constexpr int L = 5;
constexpr int S = 9;
constexpr int C = 64;
constexpr int PPB = 16;   // positions per (single-wave) block
constexpr int NCOEF = 24; // A[9], B[9], lwn[5], const

__device__ __forceinline__ float fastrcp(float v) { return __builtin_amdgcn_rcpf(v); }

__global__ __launch_bounds__(64) void mbe2_kernel(
    const float* __restrict__ x,
    const float* __restrict__ ws,
    const float* __restrict__ bs,
    const float* __restrict__ loc_emb,
    const float* __restrict__ scales,
    const float* __restrict__ locs,
    float* __restrict__ out,
    int npos)
{
    const int lane = threadIdx.x;  // 64 threads = 1 wave; lane == channel in stats/phase B

    // ---- per-lane tables ----
    float w[S], k[S], rsc[S];
    float mw[S], mk[S], vw[S], cwk2[S], vk[S];
    float le[L], lc[L];
#pragma unroll
    for (int s = 0; s < S; ++s) {
        float sc = scales[s];
        rsc[s] = fastrcp(sc);
        w[s] = ws[s * C + lane];
        k[s] = bs[s * C + lane] * sc;
    }
#pragma unroll
    for (int l = 0; l < L; ++l) {
        le[l] = loc_emb[l * C + lane];
        lc[l] = locs[l];
    }

    // ---- wave-wide LN stats per s: one-pass butterfly (Sw, Sk, Sww, Swk, Skk) ----
#pragma unroll
    for (int s = 0; s < S; ++s) {
        float a0 = w[s], a1 = k[s];
        float a2 = w[s] * w[s], a3 = w[s] * k[s], a4 = k[s] * k[s];
#pragma unroll
        for (int off = 32; off; off >>= 1) {
            a0 += __shfl_xor(a0, off);
            a1 += __shfl_xor(a1, off);
            a2 += __shfl_xor(a2, off);
            a3 += __shfl_xor(a3, off);
            a4 += __shfl_xor(a4, off);
        }
        float mww = a0 * (1.0f / 64.0f);
        float mkk = a1 * (1.0f / 64.0f);
        mw[s] = mww;
        mk[s] = mkk;
        vw[s] = fmaf(-mww, mww, a2 * (1.0f / 64.0f));
        cwk2[s] = 2.0f * fmaf(-mww, mkk, a3 * (1.0f / 64.0f));
        vk[s] = fmaf(-mkk, mkk, a4 * (1.0f / 64.0f));
    }

    __shared__ float coef[PPB][NCOEF];  // row = 96 B, 16B-aligned

    // ---- phase A: lane i < PPB computes coefficients for position pbase+i ----
    const int pbase = blockIdx.x * PPB;
    if (lane < PPB) {
        int p = pbase + lane;
        if (p < npos) {
            float xv = x[p];

            float d[L], lwv[L];
            float lwsum = 0.0f;
#pragma unroll
            for (int l = 0; l < L; ++l) {
                d[l] = xv - lc[l];
                float ad = fabsf(d[l]);
                lwv[l] = fastrcp(__logf(ad + 1.0f) + EPS_W);
                lwsum += lwv[l];
            }
            float rlw = fastrcp(lwsum);

            float A[S], Bc[S];
#pragma unroll
            for (int s = 0; s < S; ++s) { A[s] = 0.0f; Bc[s] = 0.0f; }
            float cnst = 0.0f;
            float lwn[L];

#pragma unroll
            for (int l = 0; l < L; ++l) {
                float dd = d[l];
                float ad = fabsf(dd);
                lwn[l] = lwv[l] * rlw;

                float swv[S];
                float ssum = 0.0f;
#pragma unroll
                for (int s = 0; s < S; ++s) {
                    float t = fabsf(__logf(fmaf(ad, rsc[s], EPS_W))) + EPS_W;
                    swv[s] = fastrcp(t);
                    ssum += swv[s];
                }
                float rss = fastrcp(ssum) * lwn[l];

#pragma unroll
                for (int s = 0; s < S; ++s) {
                    float mean = fmaf(dd, mw[s], mk[s]);
                    float var = fmaf(dd, fmaf(dd, vw[s], cwk2[s]), vk[s]);
                    float rstd = rsqrtf(var + LN_EPS);
                    float alpha = swv[s] * rss * rstd;
                    A[s] = fmaf(alpha, dd, A[s]);
                    Bc[s] += alpha;
                    cnst = fmaf(-alpha, mean, cnst);
                }
            }

#pragma unroll
            for (int s = 0; s < S; ++s) {
                coef[lane][s] = A[s];
                coef[lane][9 + s] = Bc[s];
            }
#pragma unroll
            for (int l = 0; l < L; ++l) coef[lane][18 + l] = lwn[l];
            coef[lane][23] = cnst;
        }
    }

    __syncthreads();

    // ---- phase B: wave applies coefficients; lane == channel, coalesced store ----
    for (int i = 0; i < PPB; ++i) {
        int p = pbase + i;
        if (p >= npos) break;
        float acc = coef[i][23];
#pragma unroll
        for (int s = 0; s < S; ++s) {
            acc = fmaf(coef[i][s], w[s], acc);
            acc = fmaf(coef[i][9 + s], k[s], acc);
        }
#pragma unroll
        for (int l = 0; l < L; ++l) acc = fmaf(coef[i][18 + l], le[l], acc);
        out[p * C + lane] = acc;
    }
}

extern "C" void kernel_launch(void* const* d_in, const int* in_sizes, int n_in,
                              void* d_out, int out_size, void* d_ws, size_t ws_size,
                              hipStream_t stream) {
    const float* x = (const float*)d_in[0];
    const float* ws = (const float*)d_in[1];
    const float* bs = (const float*)d_in[2];
    const float* loc_emb = (const float*)d_in[3];
    const float* scales = (const float*)d_in[4];
    const float* locs = (const float*)d_in[5];
    float* out = (float*)d_out;

    int npos = in_sizes[0];  // B*T = 16384
    int blocks = (npos + PPB - 1) / PPB;  // 1024 one-wave blocks
    mbe2_kernel<<<blocks, 64, 0, stream>>>(x, ws, bs, loc_emb, scales, locs, out, npos);
}